// Round 10
// baseline (289.522 us; speedup 1.0000x reference)
//
#include <hip/hip_runtime.h>
#include <hip/hip_bf16.h>
#include <math.h>

#define N_IMAGE 128
#define N_REG   36
#define DIM     1024
#define MAX_WORD 60
#define OT_ITERS 20
#define MARGIN_F 0.2f
#define ALPHA_F  0.1f
#define EPS_F    1e-12f

// fragment-major panel layout: [panel][c:16][h:2][q:4][l15:16][e:8] bf16
#define APAN  16384                    // elems per 16-row x 1024-col panel
#define AIMG  (3 * APAN)               // 3 panels per image (48 rows, 36 valid)
#define BCAP  (4 * APAN)               // 4 panels per caption (64 rows, 60 valid)

typedef short bf16x8 __attribute__((ext_vector_type(8)));
typedef float f32x4  __attribute__((ext_vector_type(4)));
typedef float f32x2  __attribute__((ext_vector_type(2)));

// ---------------- helpers ----------------

__device__ __forceinline__ unsigned int pkbf2(float a, float b) {
    union { __hip_bfloat162 h2; unsigned int u; } cv;
    cv.h2 = __float22bfloat162_rn(make_float2(a, b));
    return cv.u;
}
__device__ __forceinline__ float lo16(unsigned int u) { return __int_as_float((int)(u << 16)); }
__device__ __forceinline__ float hi16(unsigned int u) { return __int_as_float((int)(u & 0xFFFF0000u)); }

#define SWZ(x, pat) __int_as_float(__builtin_amdgcn_ds_swizzle(__float_as_int(x), (pat)))
#define BPERM(a, x) __int_as_float(__builtin_amdgcn_ds_bpermute((a), __float_as_int(x)))
#define DPPADD(x, ctrl) \
    ((x) + __int_as_float(__builtin_amdgcn_update_dpp(0, __float_as_int(x), (ctrl), 0xf, 0xf, true)))

// 16-lane group sum (all 16 lanes get the sum). DPP: lowest-latency cross-lane.
__device__ __forceinline__ float bfly16_sum(float x) {
    x = DPPADD(x, 0xB1);    // quad_perm ^1
    x = DPPADD(x, 0x4E);    // quad_perm ^2
    x = DPPADD(x, 0x124);   // row_ror:4
    x = DPPADD(x, 0x128);   // row_ror:8
    return x;
}

// cross-q reduce (lanes ^16 then ^32) — best-measured config (R2).
__device__ __forceinline__ float xq_sum(float x) {
    x += SWZ(x, 0x401F);                                   // ^16
    const int xaddr = (((int)(threadIdx.x & 63) ^ 32) << 2);
    x += BPERM(xaddr, x);                                  // ^32
    return x;
}
__device__ __forceinline__ float xq_max(float x) {
    x = fmaxf(x, SWZ(x, 0x401F));
    const int xaddr = (((int)(threadIdx.x & 63) ^ 32) << 2);
    x = fmaxf(x, BPERM(xaddr, x));
    return x;
}
// full 64-lane sum (all lanes)
__device__ __forceinline__ float bfly64_sum(float x) {
    return xq_sum(bfly16_sum(x));
}

// ------- pack: f32 row-major -> fragment-major bf16 panels + inv norms + out zero -------

__global__ __launch_bounds__(256) void pack_kernel(
    const float* __restrict__ im, const float* __restrict__ s,
    float* __restrict__ inv_im, float* __restrict__ inv_cap,
    float* __restrict__ out,
    unsigned short* __restrict__ imp, unsigned short* __restrict__ sp) {

    const int pid = blockIdx.x;
    const int tid = threadIdx.x;
    if (pid == 0 && tid == 0) { out[0] = 0.0f; out[1] = 0.0f; }

    const int w = tid >> 6, lane = tid & 63, q = lane >> 4, l15 = lane & 15;
    const bool isim = (pid < 384);
    int obj, p, nvalid;
    const float* src;
    unsigned short* dst;
    if (isim) {
        obj = pid / 3; p = pid % 3;
        src = im + (size_t)obj * 36 * DIM;
        dst = imp + (size_t)obj * AIMG + (size_t)p * APAN;
        nvalid = 36;
    } else {
        const int k = pid - 384;
        obj = k >> 2; p = k & 3;
        src = s + (size_t)obj * 60 * DIM;
        dst = sp + (size_t)obj * BCAP + (size_t)p * APAN;
        nvalid = 60;
    }
    const int row = p * 16 + l15;
    const bool valid = (row < nvalid);

    float ss = 0.0f;
    #pragma unroll
    for (int i = 0; i < 4; ++i) {
        const int c = w * 4 + i;
        #pragma unroll
        for (int h = 0; h < 2; ++h) {
            float4 v0 = make_float4(0.f, 0.f, 0.f, 0.f), v1 = v0;
            if (valid) {
                const float* rp = src + (size_t)row * DIM + c * 64 + h * 32 + q * 8;
                v0 = *(const float4*)rp;
                v1 = *(const float4*)(rp + 4);
            }
            ss += v0.x * v0.x + v0.y * v0.y + v0.z * v0.z + v0.w * v0.w
                + v1.x * v1.x + v1.y * v1.y + v1.z * v1.z + v1.w * v1.w;
            uint4 o;
            o.x = pkbf2(v0.x, v0.y); o.y = pkbf2(v0.z, v0.w);
            o.z = pkbf2(v1.x, v1.y); o.w = pkbf2(v1.z, v1.w);
            *(uint4*)(dst + (size_t)c * 1024 + h * 512 + q * 128 + l15 * 8) = o;
        }
    }
    ss = xq_sum(ss);
    __shared__ float sh[4][16];
    if (lane < 16) sh[w][lane] = ss;
    __syncthreads();
    if (tid < 16) {
        const float t = sh[0][tid] + sh[1][tid] + sh[2][tid] + sh[3][tid];
        const int r = p * 16 + tid;
        if (r < nvalid) {
            const float inv = 1.0f / (sqrtf(t) + EPS_F);
            if (isim) inv_im[obj * 36 + r] = inv;
            else      inv_cap[obj * 60 + r] = inv;
        }
    }
}

// ------- norms (fallback path only) -------

__global__ void norms_kernel(const float* __restrict__ im, const float* __restrict__ s,
                             float* __restrict__ inv_im, float* __restrict__ inv_cap,
                             float* __restrict__ out) {
    if (blockIdx.x == 0 && threadIdx.x == 0) { out[0] = 0.0f; out[1] = 0.0f; }
    const int NIM = N_IMAGE * N_REG;
    const int NS  = N_IMAGE * MAX_WORD;
    int row  = blockIdx.x * 4 + (threadIdx.x >> 6);
    int lane = threadIdx.x & 63;
    if (row >= NIM + NS) return;
    const bool isim = (row < NIM);
    const float* base = isim ? (im + (size_t)row * DIM)
                             : (s  + (size_t)(row - NIM) * DIM);
    const float4* b4 = (const float4*)base;
    float acc = 0.0f;
    for (int k = lane; k < DIM / 4; k += 64) {
        float4 v = b4[k];
        acc += v.x * v.x + v.y * v.y + v.z * v.z + v.w * v.w;
    }
    for (int off = 32; off; off >>= 1) acc += __shfl_down(acc, off, 64);
    if (lane == 0) {
        float inv = 1.0f / (sqrtf(acc) + EPS_F);
        if (isim) inv_im[row] = inv;
        else      inv_cap[row - NIM] = inv;
    }
}

// ---------------- A-matrix build (from MFMA acc -> packed A + col maxes) ----------------

template <int CT>
__device__ __forceinline__ void build_apk(
    f32x4 (&acc)[3 * CT], const float* invImS, const float* invCapS,
    int m, int wv, int q, int l15,
    unsigned int (*apk)[(CT + 1) / 2], float* mxv, bool* vw) {

    constexpr int PK = (CT + 1) / 2;
    float icap2[CT];                     // 2 * invCap (folded into the exp fma)
    #pragma unroll
    for (int ct = 0; ct < CT; ++ct) {
        const int w = ct * 16 + l15;
        vw[ct]    = (w < m);
        icap2[ct] = (w < 60) ? 2.0f * invCapS[w] : 0.0f;
    }
    #pragma unroll
    for (int ct = 0; ct < CT; ++ct) mxv[ct] = -3e38f;

    #pragma unroll
    for (int j = 0; j < 12; ++j) {
        const int rt = j >> 2, p = j & 3;
        const int r  = rt * 16 + q * 4 + p;                  // < 48
        const bool rowok = (rt < 2) || (q == 0);             // r < 36
        const float iir = rowok ? invImS[wv * 36 + (r < 36 ? r : 0)] : 0.0f;
        float av[CT];
        #pragma unroll
        for (int ct = 0; ct < CT; ++ct) {
            const float Mv = acc[rt * CT + ct][p];
            mxv[ct] = fmaxf(mxv[ct], rowok ? Mv : -3e38f);
            // A = exp(-2(1 - Mv*iir*icap)) = exp(fma(Mv, 2*iir*icap, -2))
            const bool ok = rowok && vw[ct];
            av[ct] = ok ? __expf(fmaf(Mv, iir * icap2[ct], -2.0f)) : 0.0f;
        }
        #pragma unroll
        for (int pk = 0; pk < PK; ++pk)
            apk[j][pk] = pkbf2(av[2 * pk], (2 * pk + 1 < CT) ? av[2 * pk + 1] : 0.0f);
    }

    // row-compress 12 -> 9 (rows 32..35 live at (j=8+p, q=0) -> slot (j=8, group q))
    {
        const int baddr = l15 << 2;
        #pragma unroll
        for (int pk = 0; pk < PK; ++pk) {
            const int r0 = __builtin_amdgcn_ds_bpermute(baddr, (int)apk[8][pk]);
            const int r1 = __builtin_amdgcn_ds_bpermute(baddr, (int)apk[9][pk]);
            const int r2 = __builtin_amdgcn_ds_bpermute(baddr, (int)apk[10][pk]);
            const int r3 = __builtin_amdgcn_ds_bpermute(baddr, (int)apk[11][pk]);
            const int lo = (q & 1) ? r1 : r0;
            const int hi = (q & 1) ? r3 : r2;
            apk[8][pk] = (unsigned int)((q & 2) ? hi : lo);
        }
    }
}

// ---------------- IPOT iteration core (A kept bf16-packed: -36 VGPR vs f32 copy;
// the 2 unpack ops per (j,pk) per iter trade ~12% more OT instrs for ~2x residency) ----

template <int CT>
__device__ __forceinline__ float ot_iterate(
    const unsigned int (*apk)[(CT + 1) / 2], const bool* vw, float mf, float inv_m) {

    constexpr int PK = (CT + 1) / 2;
    f32x2 t2[9][PK];
    f32x2 sig2[PK];
    #pragma unroll
    for (int pk = 0; pk < PK; ++pk) {
        const bool v0 = vw[2 * pk];
        const bool v1 = (2 * pk + 1 < CT) && vw[2 * pk + 1];
        sig2[pk].x = v0 ? inv_m : 0.0f;
        sig2[pk].y = v1 ? inv_m : 0.0f;
        #pragma unroll
        for (int j = 0; j < 9; ++j) {
            t2[j][pk].x = v0 ? mf : 0.0f;
            t2[j][pk].y = v1 ? mf : 0.0f;
        }
    }

    for (int it = 0; it < OT_ITERS; ++it) {
        f32x2 s2[PK], csum[PK];
        #pragma unroll
        for (int pk = 0; pk < PK; ++pk) {
            s2[pk]   = sig2[pk] * sig2[pk];
            csum[pk] = (f32x2){0.0f, 0.0f};
        }
        #pragma unroll
        for (int j = 0; j < 9; ++j) {
            f32x2 at[PK];
            #pragma unroll
            for (int pk = 0; pk < PK; ++pk) {
                f32x2 a2;
                a2.x = lo16(apk[j][pk]);
                a2.y = hi16(apk[j][pk]);
                at[pk] = a2 * t2[j][pk];
            }
            f32x2 u2 = at[0] * s2[0];
            #pragma unroll
            for (int pk = 1; pk < PK; ++pk) u2 += at[pk] * s2[pk];
            const float R  = bfly16_sum(u2.x + u2.y);
            const float dl = __builtin_amdgcn_rcpf(36.0f * R);
            f32x2 dl2; dl2.x = dl; dl2.y = dl;
            #pragma unroll
            for (int pk = 0; pk < PK; ++pk) {
                const f32x2 tn = at[pk] * (dl2 * sig2[pk]);
                t2[j][pk] = tn;
                csum[pk] += tn;
            }
        }
        #pragma unroll
        for (int pk = 0; pk < PK; ++pk) {
            const float cx = xq_sum(csum[pk].x);
            const float cy = xq_sum(csum[pk].y);
            const bool v0 = vw[2 * pk];
            const bool v1 = (2 * pk + 1 < CT) && vw[2 * pk + 1];
            sig2[pk].x = v0 ? __builtin_amdgcn_rcpf(mf * cx) : 0.0f;
            sig2[pk].y = v1 ? __builtin_amdgcn_rcpf(mf * cy) : 0.0f;
        }
    }

    // -sum C.T ; C = -0.5 ln(A), T = t*sig
    float pp = 0.0f;
    #pragma unroll
    for (int j = 0; j < 9; ++j) {
        #pragma unroll
        for (int pk = 0; pk < PK; ++pk) {
            const float ax = lo16(apk[j][pk]);
            const float cvx = -0.5f * __logf(fmaxf(ax, 1e-30f));
            pp = fmaf(cvx, t2[j][pk].x * sig2[pk].x, pp);
            if (2 * pk + 1 < CT) {
                const float ay = hi16(apk[j][pk]);
                const float cvy = -0.5f * __logf(fmaxf(ay, 1e-30f));
                pp = fmaf(cvy, t2[j][pk].y * sig2[pk].y, pp);
            }
        }
    }
    return bfly64_sum(pp);
}

// ---------------- MISA from mxv ----------------

template <int CT>
__device__ __forceinline__ void misa_write(
    const float* mxv, const bool* vw, float inv_m, int lane,
    float* __restrict__ S, int b, int cap) {
    float sp = 0.0f;
    #pragma unroll
    for (int ct = 0; ct < CT; ++ct) {
        float v = xq_max(mxv[ct]);
        sp += vw[ct] ? v : 0.0f;
    }
    sp = bfly64_sum(sp);                 // = 4 * sum_w colmax (q-replicated)
    if (lane == 0) S[(size_t)b * N_IMAGE + cap] = sp * inv_m * 0.25f;
}

// ---------------- GEMM core (LDS-free, single-buffered: -28 VGPR for residency;
// load latency is covered by the extra resident waves, not per-wave prefetch) ----

template <int CT>
__device__ __forceinline__ void gemm_core(
    const unsigned short* __restrict__ imp, const unsigned short* __restrict__ sp,
    int cap, int b0, int wv, int q, int l15, f32x4 (&acc)[3 * CT]) {

    const unsigned short* Ab = imp + (size_t)(b0 + wv) * AIMG + (q * 128 + l15 * 8);
    const unsigned short* Bb = sp  + (size_t)cap * BCAP        + (q * 128 + l15 * 8);

    #pragma unroll
    for (int t = 0; t < 3 * CT; ++t) acc[t] = (f32x4){0.f, 0.f, 0.f, 0.f};

    #pragma unroll 1
    for (int c = 0; c < 16; ++c) {
        #pragma unroll
        for (int h = 0; h < 2; ++h) {
            const unsigned short* Ac = Ab + c * 1024 + h * 512;
            const unsigned short* Bc = Bb + c * 1024 + h * 512;
            bf16x8 a0[3], bf0[CT];
            #pragma unroll
            for (int rt = 0; rt < 3; ++rt) a0[rt] = *(const bf16x8*)(Ac + rt * APAN);
            #pragma unroll
            for (int ct = 0; ct < CT; ++ct) bf0[ct] = *(const bf16x8*)(Bc + ct * APAN);
            #pragma unroll
            for (int rt = 0; rt < 3; ++rt)
                #pragma unroll
                for (int ct = 0; ct < CT; ++ct)
                    acc[rt * CT + ct] = __builtin_amdgcn_mfma_f32_16x16x32_bf16(
                        a0[rt], bf0[ct], acc[rt * CT + ct], 0, 0, 0);
        }
    }
}

// ---------------- fused pair kernel ----------------

template <int CT>
__device__ __forceinline__ void pair_body_fast(
    const unsigned short* __restrict__ imp, const unsigned short* __restrict__ sp,
    const float* invImS, const float* invCapS,
    int cap, int b0, int m,
    float* __restrict__ S, float* __restrict__ SOT) {

    const int tid  = threadIdx.x;
    const int lane = tid & 63;
    const int wv   = tid >> 6;
    const int q    = lane >> 4;
    const int l15  = lane & 15;
    const float mf    = (float)m;
    const float inv_m = 1.0f / mf;
    constexpr int PK = (CT + 1) / 2;

    f32x4 acc[3 * CT];
    gemm_core<CT>(imp, sp, cap, b0, wv, q, l15, acc);

    __syncthreads();

    unsigned int apk[12][PK];
    float mxv[CT]; bool vw[CT];
    build_apk<CT>(acc, invImS, invCapS, m, wv, q, l15, apk, mxv, vw);

    const int b = b0 + wv;
    misa_write<CT>(mxv, vw, inv_m, lane, S, b, cap);
    const float pp = ot_iterate<CT>(apk, vw, mf, inv_m);
    if (lane == 0) SOT[(size_t)b * N_IMAGE + cap] = -pp;
}

__global__ __launch_bounds__(256, 5)
void pair_fast(const unsigned short* __restrict__ imp,
               const unsigned short* __restrict__ sp,
               const int* __restrict__ s_l,
               const float* __restrict__ inv_im, const float* __restrict__ inv_cap,
               float* __restrict__ S, float* __restrict__ SOT) {
    const int cap = blockIdx.x;
    const int b0  = blockIdx.y * 4;
    const int tid = threadIdx.x;

    __shared__ float invImS[144];
    __shared__ float invCapS[60];
    if (tid < 144) invImS[tid] = inv_im[b0 * 36 + tid];
    else if (tid < 204) invCapS[tid - 144] = inv_cap[cap * 60 + (tid - 144)];

    const int m  = s_l[cap];
    const int CT = __builtin_amdgcn_readfirstlane((m + 15) >> 4);
    switch (CT) {
    case 1: pair_body_fast<1>(imp, sp, invImS, invCapS, cap, b0, m, S, SOT); break;
    case 2: pair_body_fast<2>(imp, sp, invImS, invCapS, cap, b0, m, S, SOT); break;
    case 3: pair_body_fast<3>(imp, sp, invImS, invCapS, cap, b0, m, S, SOT); break;
    default: pair_body_fast<4>(imp, sp, invImS, invCapS, cap, b0, m, S, SOT); break;
    }
}

// ---------------- slow fallback (f32 inputs, LDS staging) ----------------

template <int CT>
__device__ __forceinline__ void pair_body_slow(
    const float* __restrict__ im, const float* __restrict__ s,
    char* smem, const float* invImS, const float* invCapS,
    int cap, int b0, int m,
    float* __restrict__ S, float* __restrict__ SOT) {

    const int tid  = threadIdx.x;
    const int lane = tid & 63;
    const int wv   = tid >> 6;
    const int q    = lane >> 4;
    const int l15  = lane & 15;
    const int q4   = tid & 15;
    const int row0 = tid >> 4;
    const float mf    = (float)m;
    const float inv_m = 1.0f / mf;
    constexpr int PK = (CT + 1) / 2;

    const char* sA = smem;
    const char* sB = smem + 27648;

    f32x4 acc[3 * CT];
    #pragma unroll
    for (int t = 0; t < 3 * CT; ++t) acc[t] = (f32x4){0.f, 0.f, 0.f, 0.f};

    for (int c = 0; c < 16; ++c) {
        const int col = c * 64 + q4 * 4;
        #pragma unroll
        for (int img = 0; img < 4; ++img) {
            #pragma unroll
            for (int j = 0; j < 3; ++j) {
                const int r = row0 + 16 * j;
                if (j < 2 || row0 < 4) {
                    const size_t ro = (size_t)(b0 * 36 + img * 36 + r) * 1024 + col;
                    float4 v = *(const float4*)(im + ro);
                    uint2 w2; w2.x = pkbf2(v.x, v.y); w2.y = pkbf2(v.z, v.w);
                    *(uint2*)(smem + (img * 48 + r) * 144 + q4 * 8) = w2;
                }
            }
        }
        #pragma unroll
        for (int j = 0; j < CT; ++j) {
            const int r = row0 + 16 * j;
            if (CT < 4 || j < 3 || row0 < 12) {
                const size_t ro = (size_t)(cap * 60 + r) * 1024 + col;
                float4 v = *(const float4*)(s + ro);
                uint2 w2; w2.x = pkbf2(v.x, v.y); w2.y = pkbf2(v.z, v.w);
                *(uint2*)(smem + (192 + r) * 144 + q4 * 8) = w2;
            }
        }
        __syncthreads();
        #pragma unroll
        for (int h = 0; h < 2; ++h) {
            bf16x8 bfr[CT];
            #pragma unroll
            for (int ct = 0; ct < CT; ++ct)
                bfr[ct] = *(const bf16x8*)(sB + (ct * 16 + l15) * 144 + h * 64 + q * 16);
            #pragma unroll
            for (int rt = 0; rt < 3; ++rt) {
                bf16x8 afr = *(const bf16x8*)(sA + (wv * 48 + rt * 16 + l15) * 144 + h * 64 + q * 16);
                #pragma unroll
                for (int ct = 0; ct < CT; ++ct)
                    acc[rt * CT + ct] = __builtin_amdgcn_mfma_f32_16x16x32_bf16(
                        afr, bfr[ct], acc[rt * CT + ct], 0, 0, 0);
            }
        }
        __syncthreads();
    }

    unsigned int apk[12][PK];
    float mxv[CT]; bool vw[CT];
    build_apk<CT>(acc, invImS, invCapS, m, wv, q, l15, apk, mxv, vw);

    const int b = b0 + wv;
    misa_write<CT>(mxv, vw, inv_m, lane, S, b, cap);
    const float pp = ot_iterate<CT>(apk, vw, mf, inv_m);
    if (lane == 0) SOT[(size_t)b * N_IMAGE + cap] = -pp;
}

__global__ __launch_bounds__(256, 4)
void pair_slow(const float* __restrict__ im, const float* __restrict__ s,
               const int* __restrict__ s_l,
               const float* __restrict__ inv_im, const float* __restrict__ inv_cap,
               float* __restrict__ S, float* __restrict__ SOT) {
    const int cap = blockIdx.x;
    const int b0  = blockIdx.y * 4;
    const int tid = threadIdx.x;

    __shared__ __align__(16) char smem[36864];
    __shared__ float invImS[144];
    __shared__ float invCapS[60];

    if (tid < 144) invImS[tid] = inv_im[b0 * 36 + tid];
    else if (tid < 204) invCapS[tid - 144] = inv_cap[cap * 60 + (tid - 144)];

    const int m = s_l[cap];
    {
        float4 z = make_float4(0.f, 0.f, 0.f, 0.f);
        #pragma unroll
        for (int j = 0; j < 9; ++j)
            *(float4*)(smem + (tid + j * 256) * 16) = z;
    }
    __syncthreads();

    const int CT = __builtin_amdgcn_readfirstlane((m + 15) >> 4);
    switch (CT) {
    case 1: pair_body_slow<1>(im, s, smem, invImS, invCapS, cap, b0, m, S, SOT); break;
    case 2: pair_body_slow<2>(im, s, smem, invImS, invCapS, cap, b0, m, S, SOT); break;
    case 3: pair_body_slow<3>(im, s, smem, invImS, invCapS, cap, b0, m, S, SOT); break;
    default: pair_body_slow<4>(im, s, smem, invImS, invCapS, cap, b0, m, S, SOT); break;
    }
}

// ---------------- loss ----------------

__global__ void loss_kernel(const float* __restrict__ S, const float* __restrict__ SOT,
                            float* __restrict__ out) {
    const int j = blockIdx.x;
    const int t = threadIdx.x;           // 128 threads
    __shared__ float sh[4][2];
    const float db  = S[j * 129];        // diag
    const float dob = SOT[j * 129];
    float rv = 0.f, rov = 0.f, cv = 0.f, cov = 0.f;
    if (t != j) {
        float cs  = fmaxf(0.0f, MARGIN_F + S[j * 128 + t] - db);
        float cso = fmaxf(0.0f, MARGIN_F + SOT[j * 128 + t] - dob);
        rv = cs + ALPHA_F * cso;  rov = cso;
        float ci  = fmaxf(0.0f, MARGIN_F + S[t * 128 + j] - db);
        float cio = fmaxf(0.0f, MARGIN_F + SOT[t * 128 + j] - dob);
        cv = ci + ALPHA_F * cio;  cov = cio;
    }
    for (int off = 32; off; off >>= 1) {
        rv  = fmaxf(rv,  __shfl_down(rv,  off, 64));
        rov = fmaxf(rov, __shfl_down(rov, off, 64));
        cv  = fmaxf(cv,  __shfl_down(cv,  off, 64));
        cov = fmaxf(cov, __shfl_down(cov, off, 64));
    }
    if ((t & 63) == 0) {
        sh[0][t >> 6] = rv; sh[1][t >> 6] = rov;
        sh[2][t >> 6] = cv; sh[3][t >> 6] = cov;
    }
    __syncthreads();
    if (t == 0) {
        float a0 = fmaxf(sh[0][0], sh[0][1]) + fmaxf(sh[2][0], sh[2][1]);
        float a1 = fmaxf(sh[1][0], sh[1][1]) + fmaxf(sh[3][0], sh[3][1]);
        atomicAdd(&out[0], a0);
        atomicAdd(&out[1], a1);
    }
}

extern "C" void kernel_launch(void* const* d_in, const int* in_sizes, int n_in,
                              void* d_out, int out_size, void* d_ws, size_t ws_size,
                              hipStream_t stream) {
    const float* im  = (const float*)d_in[0];
    const float* s   = (const float*)d_in[1];
    const int*   s_l = (const int*)d_in[2];
    float* out = (float*)d_out;
    float* ws  = (float*)d_ws;

    float* inv_im  = ws;
    float* inv_cap = ws + 4608;
    float* S       = ws + 12288;
    float* SOT     = ws + 28672;
    // bf16 panels after the 180224-byte float region
    unsigned short* imp = (unsigned short*)((char*)d_ws + 180224);
    unsigned short* sp  = imp + (size_t)N_IMAGE * AIMG;
    const size_t need_fast = 180224 +
        ((size_t)N_IMAGE * AIMG + (size_t)N_IMAGE * BCAP) * 2;   // 29,540,352

    if (ws_size >= need_fast) {
        pack_kernel<<<dim3(896), dim3(256), 0, stream>>>(
            im, s, inv_im, inv_cap, out, imp, sp);
        pair_fast<<<dim3(N_IMAGE, N_IMAGE / 4), dim3(256), 0, stream>>>(
            imp, sp, s_l, inv_im, inv_cap, S, SOT);
    } else {
        norms_kernel<<<dim3((4608 + 7680) / 4), dim3(256), 0, stream>>>(
            im, s, inv_im, inv_cap, out);
        pair_slow<<<dim3(N_IMAGE, N_IMAGE / 4), dim3(256), 0, stream>>>(
            im, s, s_l, inv_im, inv_cap, S, SOT);
    }
    loss_kernel<<<dim3(N_IMAGE), dim3(128), 0, stream>>>(S, SOT, out);
}

// Round 11
// 263.557 us; speedup vs baseline: 1.0985x; 1.0985x over previous
//
#include <hip/hip_runtime.h>
#include <hip/hip_bf16.h>
#include <math.h>

#define N_IMAGE 128
#define N_REG   36
#define DIM     1024
#define MAX_WORD 60
#define OT_ITERS 20
#define MARGIN_F 0.2f
#define ALPHA_F  0.1f
#define EPS_F    1e-12f

// fragment-major panel layout: [panel][c:16][h:2][q:4][l15:16][e:8] bf16
#define APAN  16384                    // elems per 16-row x 1024-col panel
#define AIMG  (3 * APAN)               // 3 panels per image (48 rows, 36 valid)
#define BCAP  (4 * APAN)               // 4 panels per caption (64 rows, 60 valid)

typedef short bf16x8 __attribute__((ext_vector_type(8)));
typedef float f32x4  __attribute__((ext_vector_type(4)));
typedef float f32x2  __attribute__((ext_vector_type(2)));

// ---------------- helpers ----------------

__device__ __forceinline__ unsigned int pkbf2(float a, float b) {
    union { __hip_bfloat162 h2; unsigned int u; } cv;
    cv.h2 = __float22bfloat162_rn(make_float2(a, b));
    return cv.u;
}
__device__ __forceinline__ float lo16(unsigned int u) { return __int_as_float((int)(u << 16)); }
__device__ __forceinline__ float hi16(unsigned int u) { return __int_as_float((int)(u & 0xFFFF0000u)); }

#define SWZ(x, pat) __int_as_float(__builtin_amdgcn_ds_swizzle(__float_as_int(x), (pat)))
#define BPERM(a, x) __int_as_float(__builtin_amdgcn_ds_bpermute((a), __float_as_int(x)))
#define DPPADD(x, ctrl) \
    ((x) + __int_as_float(__builtin_amdgcn_update_dpp(0, __float_as_int(x), (ctrl), 0xf, 0xf, true)))

// 16-lane group sum (all 16 lanes get the sum). DPP: lowest-latency cross-lane.
__device__ __forceinline__ float bfly16_sum(float x) {
    x = DPPADD(x, 0xB1);    // quad_perm ^1
    x = DPPADD(x, 0x4E);    // quad_perm ^2
    x = DPPADD(x, 0x124);   // row_ror:4
    x = DPPADD(x, 0x128);   // row_ror:8
    return x;
}

// cross-q reduce (lanes ^16 then ^32) — best-measured config (R2).
__device__ __forceinline__ float xq_sum(float x) {
    x += SWZ(x, 0x401F);                                   // ^16
    const int xaddr = (((int)(threadIdx.x & 63) ^ 32) << 2);
    x += BPERM(xaddr, x);                                  // ^32
    return x;
}
__device__ __forceinline__ float xq_max(float x) {
    x = fmaxf(x, SWZ(x, 0x401F));
    const int xaddr = (((int)(threadIdx.x & 63) ^ 32) << 2);
    x = fmaxf(x, BPERM(xaddr, x));
    return x;
}
// full 64-lane sum (all lanes)
__device__ __forceinline__ float bfly64_sum(float x) {
    return xq_sum(bfly16_sum(x));
}

// ------- LPT sort: perm[rank] = cap, rank by m descending (stable) -------
// Heavy (CT=4) blocks dispatch first; the grid tail is the lightest captions.

__global__ void sort_kernel(const int* __restrict__ s_l, int* __restrict__ perm) {
    const int t = threadIdx.x;           // 128 threads, 1 block
    const int mt = s_l[t];
    int rank = 0;
    for (int j = 0; j < N_IMAGE; ++j) {
        const int mj = s_l[j];
        rank += (mj > mt) || (mj == mt && j < t);
    }
    perm[rank] = t;
}

// ------- pack: f32 row-major -> fragment-major bf16 panels + inv norms + out zero -------

__global__ __launch_bounds__(256) void pack_kernel(
    const float* __restrict__ im, const float* __restrict__ s,
    float* __restrict__ inv_im, float* __restrict__ inv_cap,
    float* __restrict__ out,
    unsigned short* __restrict__ imp, unsigned short* __restrict__ sp) {

    const int pid = blockIdx.x;
    const int tid = threadIdx.x;
    if (pid == 0 && tid == 0) { out[0] = 0.0f; out[1] = 0.0f; }

    const int w = tid >> 6, lane = tid & 63, q = lane >> 4, l15 = lane & 15;
    const bool isim = (pid < 384);
    int obj, p, nvalid;
    const float* src;
    unsigned short* dst;
    if (isim) {
        obj = pid / 3; p = pid % 3;
        src = im + (size_t)obj * 36 * DIM;
        dst = imp + (size_t)obj * AIMG + (size_t)p * APAN;
        nvalid = 36;
    } else {
        const int k = pid - 384;
        obj = k >> 2; p = k & 3;
        src = s + (size_t)obj * 60 * DIM;
        dst = sp + (size_t)obj * BCAP + (size_t)p * APAN;
        nvalid = 60;
    }
    const int row = p * 16 + l15;
    const bool valid = (row < nvalid);

    float ss = 0.0f;
    #pragma unroll
    for (int i = 0; i < 4; ++i) {
        const int c = w * 4 + i;
        #pragma unroll
        for (int h = 0; h < 2; ++h) {
            float4 v0 = make_float4(0.f, 0.f, 0.f, 0.f), v1 = v0;
            if (valid) {
                const float* rp = src + (size_t)row * DIM + c * 64 + h * 32 + q * 8;
                v0 = *(const float4*)rp;
                v1 = *(const float4*)(rp + 4);
            }
            ss += v0.x * v0.x + v0.y * v0.y + v0.z * v0.z + v0.w * v0.w
                + v1.x * v1.x + v1.y * v1.y + v1.z * v1.z + v1.w * v1.w;
            uint4 o;
            o.x = pkbf2(v0.x, v0.y); o.y = pkbf2(v0.z, v0.w);
            o.z = pkbf2(v1.x, v1.y); o.w = pkbf2(v1.z, v1.w);
            *(uint4*)(dst + (size_t)c * 1024 + h * 512 + q * 128 + l15 * 8) = o;
        }
    }
    ss = xq_sum(ss);
    __shared__ float sh[4][16];
    if (lane < 16) sh[w][lane] = ss;
    __syncthreads();
    if (tid < 16) {
        const float t = sh[0][tid] + sh[1][tid] + sh[2][tid] + sh[3][tid];
        const int r = p * 16 + tid;
        if (r < nvalid) {
            const float inv = 1.0f / (sqrtf(t) + EPS_F);
            if (isim) inv_im[obj * 36 + r] = inv;
            else      inv_cap[obj * 60 + r] = inv;
        }
    }
}

// ------- norms (fallback path only) -------

__global__ void norms_kernel(const float* __restrict__ im, const float* __restrict__ s,
                             float* __restrict__ inv_im, float* __restrict__ inv_cap,
                             float* __restrict__ out) {
    if (blockIdx.x == 0 && threadIdx.x == 0) { out[0] = 0.0f; out[1] = 0.0f; }
    const int NIM = N_IMAGE * N_REG;
    const int NS  = N_IMAGE * MAX_WORD;
    int row  = blockIdx.x * 4 + (threadIdx.x >> 6);
    int lane = threadIdx.x & 63;
    if (row >= NIM + NS) return;
    const bool isim = (row < NIM);
    const float* base = isim ? (im + (size_t)row * DIM)
                             : (s  + (size_t)(row - NIM) * DIM);
    const float4* b4 = (const float4*)base;
    float acc = 0.0f;
    for (int k = lane; k < DIM / 4; k += 64) {
        float4 v = b4[k];
        acc += v.x * v.x + v.y * v.y + v.z * v.z + v.w * v.w;
    }
    for (int off = 32; off; off >>= 1) acc += __shfl_down(acc, off, 64);
    if (lane == 0) {
        float inv = 1.0f / (sqrtf(acc) + EPS_F);
        if (isim) inv_im[row] = inv;
        else      inv_cap[row - NIM] = inv;
    }
}

// ---------------- A-matrix build (from MFMA acc -> packed A + col maxes) ----------------

template <int CT>
__device__ __forceinline__ void build_apk(
    f32x4 (&acc)[3 * CT], const float* invImS, const float* invCapS,
    int m, int wv, int q, int l15,
    unsigned int (*apk)[(CT + 1) / 2], float* mxv, bool* vw) {

    constexpr int PK = (CT + 1) / 2;
    float icap2[CT];                     // 2 * invCap (folded into the exp fma)
    #pragma unroll
    for (int ct = 0; ct < CT; ++ct) {
        const int w = ct * 16 + l15;
        vw[ct]    = (w < m);
        icap2[ct] = (w < 60) ? 2.0f * invCapS[w] : 0.0f;
    }
    #pragma unroll
    for (int ct = 0; ct < CT; ++ct) mxv[ct] = -3e38f;

    #pragma unroll
    for (int j = 0; j < 12; ++j) {
        const int rt = j >> 2, p = j & 3;
        const int r  = rt * 16 + q * 4 + p;                  // < 48
        const bool rowok = (rt < 2) || (q == 0);             // r < 36
        const float iir = rowok ? invImS[wv * 36 + (r < 36 ? r : 0)] : 0.0f;
        float av[CT];
        #pragma unroll
        for (int ct = 0; ct < CT; ++ct) {
            const float Mv = acc[rt * CT + ct][p];
            mxv[ct] = fmaxf(mxv[ct], rowok ? Mv : -3e38f);
            // A = exp(-2(1 - Mv*iir*icap)) = exp(fma(Mv, 2*iir*icap, -2))
            const bool ok = rowok && vw[ct];
            av[ct] = ok ? __expf(fmaf(Mv, iir * icap2[ct], -2.0f)) : 0.0f;
        }
        #pragma unroll
        for (int pk = 0; pk < PK; ++pk)
            apk[j][pk] = pkbf2(av[2 * pk], (2 * pk + 1 < CT) ? av[2 * pk + 1] : 0.0f);
    }

    // row-compress 12 -> 9 (rows 32..35 live at (j=8+p, q=0) -> slot (j=8, group q))
    {
        const int baddr = l15 << 2;
        #pragma unroll
        for (int pk = 0; pk < PK; ++pk) {
            const int r0 = __builtin_amdgcn_ds_bpermute(baddr, (int)apk[8][pk]);
            const int r1 = __builtin_amdgcn_ds_bpermute(baddr, (int)apk[9][pk]);
            const int r2 = __builtin_amdgcn_ds_bpermute(baddr, (int)apk[10][pk]);
            const int r3 = __builtin_amdgcn_ds_bpermute(baddr, (int)apk[11][pk]);
            const int lo = (q & 1) ? r1 : r0;
            const int hi = (q & 1) ? r3 : r2;
            apk[8][pk] = (unsigned int)((q & 2) ? hi : lo);
        }
    }
}

// ---------------- IPOT iteration core ----------------

template <int CT>
__device__ __forceinline__ float ot_iterate(
    f32x2 (*af)[(CT + 1) / 2], const bool* vw, float mf, float inv_m) {

    constexpr int PK = (CT + 1) / 2;
    f32x2 t2[9][PK];
    f32x2 sig2[PK];
    #pragma unroll
    for (int pk = 0; pk < PK; ++pk) {
        const bool v0 = vw[2 * pk];
        const bool v1 = (2 * pk + 1 < CT) && vw[2 * pk + 1];
        sig2[pk].x = v0 ? inv_m : 0.0f;
        sig2[pk].y = v1 ? inv_m : 0.0f;
        #pragma unroll
        for (int j = 0; j < 9; ++j) {
            t2[j][pk].x = v0 ? mf : 0.0f;
            t2[j][pk].y = v1 ? mf : 0.0f;
        }
    }

    for (int it = 0; it < OT_ITERS; ++it) {
        f32x2 s2[PK], csum[PK];
        #pragma unroll
        for (int pk = 0; pk < PK; ++pk) {
            s2[pk]   = sig2[pk] * sig2[pk];
            csum[pk] = (f32x2){0.0f, 0.0f};
        }
        #pragma unroll
        for (int j = 0; j < 9; ++j) {
            f32x2 at[PK];
            #pragma unroll
            for (int pk = 0; pk < PK; ++pk)
                at[pk] = af[j][pk] * t2[j][pk];
            f32x2 u2 = at[0] * s2[0];
            #pragma unroll
            for (int pk = 1; pk < PK; ++pk) u2 += at[pk] * s2[pk];
            const float R  = bfly16_sum(u2.x + u2.y);
            const float dl = __builtin_amdgcn_rcpf(36.0f * R);
            f32x2 dl2; dl2.x = dl; dl2.y = dl;
            #pragma unroll
            for (int pk = 0; pk < PK; ++pk) {
                const f32x2 tn = at[pk] * (dl2 * sig2[pk]);
                t2[j][pk] = tn;
                csum[pk] += tn;
            }
        }
        #pragma unroll
        for (int pk = 0; pk < PK; ++pk) {
            const float cx = xq_sum(csum[pk].x);
            const float cy = xq_sum(csum[pk].y);
            const bool v0 = vw[2 * pk];
            const bool v1 = (2 * pk + 1 < CT) && vw[2 * pk + 1];
            sig2[pk].x = v0 ? __builtin_amdgcn_rcpf(mf * cx) : 0.0f;
            sig2[pk].y = v1 ? __builtin_amdgcn_rcpf(mf * cy) : 0.0f;
        }
    }

    // -sum C.T ; C = -0.5 ln(A), T = t*sig
    float pp = 0.0f;
    #pragma unroll
    for (int j = 0; j < 9; ++j) {
        #pragma unroll
        for (int pk = 0; pk < PK; ++pk) {
            const float cvx = -0.5f * __logf(fmaxf(af[j][pk].x, 1e-30f));
            pp = fmaf(cvx, t2[j][pk].x * sig2[pk].x, pp);
            if (2 * pk + 1 < CT) {
                const float cvy = -0.5f * __logf(fmaxf(af[j][pk].y, 1e-30f));
                pp = fmaf(cvy, t2[j][pk].y * sig2[pk].y, pp);
            }
        }
    }
    return bfly64_sum(pp);
}

// ---------------- MISA from mxv ----------------

template <int CT>
__device__ __forceinline__ void misa_write(
    const float* mxv, const bool* vw, float inv_m, int lane,
    float* __restrict__ S, int b, int cap) {
    float sp = 0.0f;
    #pragma unroll
    for (int ct = 0; ct < CT; ++ct) {
        float v = xq_max(mxv[ct]);
        sp += vw[ct] ? v : 0.0f;
    }
    sp = bfly64_sum(sp);                 // = 4 * sum_w colmax (q-replicated)
    if (lane == 0) S[(size_t)b * N_IMAGE + cap] = sp * inv_m * 0.25f;
}

// ---------------- GEMM core (LDS-free, double-buffered — best-measured R2/R4) ----

template <int CT>
__device__ __forceinline__ void gemm_core(
    const unsigned short* __restrict__ imp, const unsigned short* __restrict__ sp,
    int cap, int b0, int wv, int q, int l15, f32x4 (&acc)[3 * CT]) {

    const unsigned short* Ab = imp + (size_t)(b0 + wv) * AIMG + (q * 128 + l15 * 8);
    const unsigned short* Bb = sp  + (size_t)cap * BCAP        + (q * 128 + l15 * 8);

    #pragma unroll
    for (int t = 0; t < 3 * CT; ++t) acc[t] = (f32x4){0.f, 0.f, 0.f, 0.f};

    bf16x8 a0[3], bf0[CT], a1[3], bf1[CT];
    #pragma unroll
    for (int rt = 0; rt < 3; ++rt) a0[rt] = *(const bf16x8*)(Ab + rt * APAN);
    #pragma unroll
    for (int ct = 0; ct < CT; ++ct) bf0[ct] = *(const bf16x8*)(Bb + ct * APAN);

    #pragma unroll 1
    for (int c = 0; c < 16; ++c) {
        const unsigned short* Ac = Ab + c * 1024;
        const unsigned short* Bc = Bb + c * 1024;
        #pragma unroll
        for (int rt = 0; rt < 3; ++rt) a1[rt] = *(const bf16x8*)(Ac + rt * APAN + 512);
        #pragma unroll
        for (int ct = 0; ct < CT; ++ct) bf1[ct] = *(const bf16x8*)(Bc + ct * APAN + 512);
        #pragma unroll
        for (int rt = 0; rt < 3; ++rt)
            #pragma unroll
            for (int ct = 0; ct < CT; ++ct)
                acc[rt * CT + ct] = __builtin_amdgcn_mfma_f32_16x16x32_bf16(
                    a0[rt], bf0[ct], acc[rt * CT + ct], 0, 0, 0);
        const int cn = (c < 15) ? c + 1 : 15;
        const unsigned short* An = Ab + cn * 1024;
        const unsigned short* Bn = Bb + cn * 1024;
        #pragma unroll
        for (int rt = 0; rt < 3; ++rt) a0[rt] = *(const bf16x8*)(An + rt * APAN);
        #pragma unroll
        for (int ct = 0; ct < CT; ++ct) bf0[ct] = *(const bf16x8*)(Bn + ct * APAN);
        #pragma unroll
        for (int rt = 0; rt < 3; ++rt)
            #pragma unroll
            for (int ct = 0; ct < CT; ++ct)
                acc[rt * CT + ct] = __builtin_amdgcn_mfma_f32_16x16x32_bf16(
                    a1[rt], bf1[ct], acc[rt * CT + ct], 0, 0, 0);
    }
}

// ---------------- fused pair kernel (LPT-ordered 1D grid) ----------------

template <int CT>
__device__ __forceinline__ void pair_body_fast(
    const unsigned short* __restrict__ imp, const unsigned short* __restrict__ sp,
    const float* invImS, const float* invCapS,
    int cap, int b0, int m,
    float* __restrict__ S, float* __restrict__ SOT) {

    const int tid  = threadIdx.x;
    const int lane = tid & 63;
    const int wv   = tid >> 6;
    const int q    = lane >> 4;
    const int l15  = lane & 15;
    const float mf    = (float)m;
    const float inv_m = 1.0f / mf;
    constexpr int PK = (CT + 1) / 2;

    f32x4 acc[3 * CT];
    gemm_core<CT>(imp, sp, cap, b0, wv, q, l15, acc);

    __syncthreads();

    unsigned int apk[12][PK];
    float mxv[CT]; bool vw[CT];
    build_apk<CT>(acc, invImS, invCapS, m, wv, q, l15, apk, mxv, vw);

    f32x2 af[9][PK];
    #pragma unroll
    for (int j = 0; j < 9; ++j)
        #pragma unroll
        for (int pk = 0; pk < PK; ++pk) {
            af[j][pk].x = lo16(apk[j][pk]);
            af[j][pk].y = hi16(apk[j][pk]);
        }

    const int b = b0 + wv;
    misa_write<CT>(mxv, vw, inv_m, lane, S, b, cap);
    const float pp = ot_iterate<CT>(af, vw, mf, inv_m);
    if (lane == 0) SOT[(size_t)b * N_IMAGE + cap] = -pp;
}

__global__ __launch_bounds__(256, 4)
void pair_fast(const unsigned short* __restrict__ imp,
               const unsigned short* __restrict__ sp,
               const int* __restrict__ s_l,
               const int* __restrict__ perm,
               const float* __restrict__ inv_im, const float* __restrict__ inv_cap,
               float* __restrict__ S, float* __restrict__ SOT) {
    // LPT order: blocks for the heaviest captions (largest m) dispatch first;
    // the grid tail is the lightest captions -> short drain tail.
    const int bid = blockIdx.x;              // [0, 4096)
    const int cap = perm[bid >> 5];          // sorted-descending caption
    const int b0  = (bid & 31) * 4;          // image group
    const int tid = threadIdx.x;

    __shared__ float invImS[144];
    __shared__ float invCapS[60];
    if (tid < 144) invImS[tid] = inv_im[b0 * 36 + tid];
    else if (tid < 204) invCapS[tid - 144] = inv_cap[cap * 60 + (tid - 144)];

    const int m  = s_l[cap];
    const int CT = __builtin_amdgcn_readfirstlane((m + 15) >> 4);
    switch (CT) {
    case 1: pair_body_fast<1>(imp, sp, invImS, invCapS, cap, b0, m, S, SOT); break;
    case 2: pair_body_fast<2>(imp, sp, invImS, invCapS, cap, b0, m, S, SOT); break;
    case 3: pair_body_fast<3>(imp, sp, invImS, invCapS, cap, b0, m, S, SOT); break;
    default: pair_body_fast<4>(imp, sp, invImS, invCapS, cap, b0, m, S, SOT); break;
    }
}

// ---------------- slow fallback (f32 inputs, LDS staging) ----------------

template <int CT>
__device__ __forceinline__ void pair_body_slow(
    const float* __restrict__ im, const float* __restrict__ s,
    char* smem, const float* invImS, const float* invCapS,
    int cap, int b0, int m,
    float* __restrict__ S, float* __restrict__ SOT) {

    const int tid  = threadIdx.x;
    const int lane = tid & 63;
    const int wv   = tid >> 6;
    const int q    = lane >> 4;
    const int l15  = lane & 15;
    const int q4   = tid & 15;
    const int row0 = tid >> 4;
    const float mf    = (float)m;
    const float inv_m = 1.0f / mf;
    constexpr int PK = (CT + 1) / 2;

    const char* sA = smem;
    const char* sB = smem + 27648;

    f32x4 acc[3 * CT];
    #pragma unroll
    for (int t = 0; t < 3 * CT; ++t) acc[t] = (f32x4){0.f, 0.f, 0.f, 0.f};

    for (int c = 0; c < 16; ++c) {
        const int col = c * 64 + q4 * 4;
        #pragma unroll
        for (int img = 0; img < 4; ++img) {
            #pragma unroll
            for (int j = 0; j < 3; ++j) {
                const int r = row0 + 16 * j;
                if (j < 2 || row0 < 4) {
                    const size_t ro = (size_t)(b0 * 36 + img * 36 + r) * 1024 + col;
                    float4 v = *(const float4*)(im + ro);
                    uint2 w2; w2.x = pkbf2(v.x, v.y); w2.y = pkbf2(v.z, v.w);
                    *(uint2*)(smem + (img * 48 + r) * 144 + q4 * 8) = w2;
                }
            }
        }
        #pragma unroll
        for (int j = 0; j < CT; ++j) {
            const int r = row0 + 16 * j;
            if (CT < 4 || j < 3 || row0 < 12) {
                const size_t ro = (size_t)(cap * 60 + r) * 1024 + col;
                float4 v = *(const float4*)(s + ro);
                uint2 w2; w2.x = pkbf2(v.x, v.y); w2.y = pkbf2(v.z, v.w);
                *(uint2*)(smem + (192 + r) * 144 + q4 * 8) = w2;
            }
        }
        __syncthreads();
        #pragma unroll
        for (int h = 0; h < 2; ++h) {
            bf16x8 bfr[CT];
            #pragma unroll
            for (int ct = 0; ct < CT; ++ct)
                bfr[ct] = *(const bf16x8*)(sB + (ct * 16 + l15) * 144 + h * 64 + q * 16);
            #pragma unroll
            for (int rt = 0; rt < 3; ++rt) {
                bf16x8 afr = *(const bf16x8*)(sA + (wv * 48 + rt * 16 + l15) * 144 + h * 64 + q * 16);
                #pragma unroll
                for (int ct = 0; ct < CT; ++ct)
                    acc[rt * CT + ct] = __builtin_amdgcn_mfma_f32_16x16x32_bf16(
                        afr, bfr[ct], acc[rt * CT + ct], 0, 0, 0);
            }
        }
        __syncthreads();
    }

    unsigned int apk[12][PK];
    float mxv[CT]; bool vw[CT];
    build_apk<CT>(acc, invImS, invCapS, m, wv, q, l15, apk, mxv, vw);

    f32x2 af[9][PK];
    #pragma unroll
    for (int j = 0; j < 9; ++j)
        #pragma unroll
        for (int pk = 0; pk < PK; ++pk) {
            af[j][pk].x = lo16(apk[j][pk]);
            af[j][pk].y = hi16(apk[j][pk]);
        }

    const int b = b0 + wv;
    misa_write<CT>(mxv, vw, inv_m, lane, S, b, cap);
    const float pp = ot_iterate<CT>(af, vw, mf, inv_m);
    if (lane == 0) SOT[(size_t)b * N_IMAGE + cap] = -pp;
}

__global__ __launch_bounds__(256, 4)
void pair_slow(const float* __restrict__ im, const float* __restrict__ s,
               const int* __restrict__ s_l,
               const float* __restrict__ inv_im, const float* __restrict__ inv_cap,
               float* __restrict__ S, float* __restrict__ SOT) {
    const int cap = blockIdx.x;
    const int b0  = blockIdx.y * 4;
    const int tid = threadIdx.x;

    __shared__ __align__(16) char smem[36864];
    __shared__ float invImS[144];
    __shared__ float invCapS[60];

    if (tid < 144) invImS[tid] = inv_im[b0 * 36 + tid];
    else if (tid < 204) invCapS[tid - 144] = inv_cap[cap * 60 + (tid - 144)];

    const int m = s_l[cap];
    {
        float4 z = make_float4(0.f, 0.f, 0.f, 0.f);
        #pragma unroll
        for (int j = 0; j < 9; ++j)
            *(float4*)(smem + (tid + j * 256) * 16) = z;
    }
    __syncthreads();

    const int CT = __builtin_amdgcn_readfirstlane((m + 15) >> 4);
    switch (CT) {
    case 1: pair_body_slow<1>(im, s, smem, invImS, invCapS, cap, b0, m, S, SOT); break;
    case 2: pair_body_slow<2>(im, s, smem, invImS, invCapS, cap, b0, m, S, SOT); break;
    case 3: pair_body_slow<3>(im, s, smem, invImS, invCapS, cap, b0, m, S, SOT); break;
    default: pair_body_slow<4>(im, s, smem, invImS, invCapS, cap, b0, m, S, SOT); break;
    }
}

// ---------------- loss ----------------

__global__ void loss_kernel(const float* __restrict__ S, const float* __restrict__ SOT,
                            float* __restrict__ out) {
    const int j = blockIdx.x;
    const int t = threadIdx.x;           // 128 threads
    __shared__ float sh[4][2];
    const float db  = S[j * 129];        // diag
    const float dob = SOT[j * 129];
    float rv = 0.f, rov = 0.f, cv = 0.f, cov = 0.f;
    if (t != j) {
        float cs  = fmaxf(0.0f, MARGIN_F + S[j * 128 + t] - db);
        float cso = fmaxf(0.0f, MARGIN_F + SOT[j * 128 + t] - dob);
        rv = cs + ALPHA_F * cso;  rov = cso;
        float ci  = fmaxf(0.0f, MARGIN_F + S[t * 128 + j] - db);
        float cio = fmaxf(0.0f, MARGIN_F + SOT[t * 128 + j] - dob);
        cv = ci + ALPHA_F * cio;  cov = cio;
    }
    for (int off = 32; off; off >>= 1) {
        rv  = fmaxf(rv,  __shfl_down(rv,  off, 64));
        rov = fmaxf(rov, __shfl_down(rov, off, 64));
        cv  = fmaxf(cv,  __shfl_down(cv,  off, 64));
        cov = fmaxf(cov, __shfl_down(cov, off, 64));
    }
    if ((t & 63) == 0) {
        sh[0][t >> 6] = rv; sh[1][t >> 6] = rov;
        sh[2][t >> 6] = cv; sh[3][t >> 6] = cov;
    }
    __syncthreads();
    if (t == 0) {
        float a0 = fmaxf(sh[0][0], sh[0][1]) + fmaxf(sh[2][0], sh[2][1]);
        float a1 = fmaxf(sh[1][0], sh[1][1]) + fmaxf(sh[3][0], sh[3][1]);
        atomicAdd(&out[0], a0);
        atomicAdd(&out[1], a1);
    }
}

extern "C" void kernel_launch(void* const* d_in, const int* in_sizes, int n_in,
                              void* d_out, int out_size, void* d_ws, size_t ws_size,
                              hipStream_t stream) {
    const float* im  = (const float*)d_in[0];
    const float* s   = (const float*)d_in[1];
    const int*   s_l = (const int*)d_in[2];
    float* out = (float*)d_out;
    float* ws  = (float*)d_ws;

    float* inv_im  = ws;
    float* inv_cap = ws + 4608;
    float* S       = ws + 12288;
    float* SOT     = ws + 28672;
    int*   perm    = (int*)(ws + 45056);                     // 128 ints
    // bf16 panels after the float+perm region (512 B for perm)
    unsigned short* imp = (unsigned short*)((char*)d_ws + 180736);
    unsigned short* sp  = imp + (size_t)N_IMAGE * AIMG;
    const size_t need_fast = 180736 +
        ((size_t)N_IMAGE * AIMG + (size_t)N_IMAGE * BCAP) * 2;   // 29,540,864

    if (ws_size >= need_fast) {
        sort_kernel<<<dim3(1), dim3(128), 0, stream>>>(s_l, perm);
        pack_kernel<<<dim3(896), dim3(256), 0, stream>>>(
            im, s, inv_im, inv_cap, out, imp, sp);
        pair_fast<<<dim3(N_IMAGE * N_IMAGE / 4), dim3(256), 0, stream>>>(
            imp, sp, s_l, perm, inv_im, inv_cap, S, SOT);
    } else {
        norms_kernel<<<dim3((4608 + 7680) / 4), dim3(256), 0, stream>>>(
            im, s, inv_im, inv_cap, out);
        pair_slow<<<dim3(N_IMAGE, N_IMAGE / 4), dim3(256), 0, stream>>>(
            im, s, s_l, inv_im, inv_cap, S, SOT);
    }
    loss_kernel<<<dim3(N_IMAGE), dim3(128), 0, stream>>>(S, SOT, out);
}

// Round 12
// 257.856 us; speedup vs baseline: 1.1228x; 1.0221x over previous
//
#include <hip/hip_runtime.h>
#include <hip/hip_bf16.h>
#include <math.h>

#define N_IMAGE 128
#define N_REG   36
#define DIM     1024
#define MAX_WORD 60
#define OT_ITERS 20
#define MARGIN_F 0.2f
#define ALPHA_F  0.1f
#define EPS_F    1e-12f

// fragment-major panel layout: [panel][c:16][h:2][q:4][l15:16][e:8] bf16
#define APAN  16384                    // elems per 16-row x 1024-col panel
#define AIMG  (3 * APAN)               // 3 panels per image (48 rows, 36 valid)
#define BCAP  (4 * APAN)               // 4 panels per caption (64 rows, 60 valid)

typedef short bf16x8 __attribute__((ext_vector_type(8)));
typedef float f32x4  __attribute__((ext_vector_type(4)));
typedef float f32x2  __attribute__((ext_vector_type(2)));

// ---------------- helpers ----------------

__device__ __forceinline__ unsigned int pkbf2(float a, float b) {
    union { __hip_bfloat162 h2; unsigned int u; } cv;
    cv.h2 = __float22bfloat162_rn(make_float2(a, b));
    return cv.u;
}
__device__ __forceinline__ float lo16(unsigned int u) { return __int_as_float((int)(u << 16)); }
__device__ __forceinline__ float hi16(unsigned int u) { return __int_as_float((int)(u & 0xFFFF0000u)); }

#define SWZ(x, pat) __int_as_float(__builtin_amdgcn_ds_swizzle(__float_as_int(x), (pat)))
#define BPERM(a, x) __int_as_float(__builtin_amdgcn_ds_bpermute((a), __float_as_int(x)))
#define DPPADD(x, ctrl) \
    ((x) + __int_as_float(__builtin_amdgcn_update_dpp(0, __float_as_int(x), (ctrl), 0xf, 0xf, true)))

// 16-lane group sum (all 16 lanes get the sum). DPP: lowest-latency cross-lane.
__device__ __forceinline__ float bfly16_sum(float x) {
    x = DPPADD(x, 0xB1);    // quad_perm ^1
    x = DPPADD(x, 0x4E);    // quad_perm ^2
    x = DPPADD(x, 0x124);   // row_ror:4
    x = DPPADD(x, 0x128);   // row_ror:8
    return x;
}

// cross-q reduce (lanes ^16 then ^32) — best-measured config (R2).
__device__ __forceinline__ float xq_sum(float x) {
    x += SWZ(x, 0x401F);                                   // ^16
    const int xaddr = (((int)(threadIdx.x & 63) ^ 32) << 2);
    x += BPERM(xaddr, x);                                  // ^32
    return x;
}
__device__ __forceinline__ float xq_max(float x) {
    x = fmaxf(x, SWZ(x, 0x401F));
    const int xaddr = (((int)(threadIdx.x & 63) ^ 32) << 2);
    x = fmaxf(x, BPERM(xaddr, x));
    return x;
}
// full 64-lane sum (all lanes)
__device__ __forceinline__ float bfly64_sum(float x) {
    return xq_sum(bfly16_sum(x));
}

// ------- pack: f32 row-major -> fragment-major bf16 panels + inv norms + out zero.
// Block 896 computes the LPT permutation concurrently (perm[rank]=cap, m desc),
// removing the separate serial sort launch from the graph chain.

__global__ __launch_bounds__(256) void pack_kernel(
    const float* __restrict__ im, const float* __restrict__ s,
    float* __restrict__ inv_im, float* __restrict__ inv_cap,
    float* __restrict__ out,
    unsigned short* __restrict__ imp, unsigned short* __restrict__ sp,
    const int* __restrict__ s_l, int* __restrict__ perm) {

    const int pid = blockIdx.x;
    const int tid = threadIdx.x;

    if (pid == 896) {                    // LPT rank block (concurrent with pack)
        if (tid < N_IMAGE) {
            const int mt = s_l[tid];
            int rank = 0;
            for (int j = 0; j < N_IMAGE; ++j) {
                const int mj = s_l[j];
                rank += (mj > mt) || (mj == mt && j < tid);
            }
            perm[rank] = tid;
        }
        return;
    }
    if (pid == 0 && tid == 0) { out[0] = 0.0f; out[1] = 0.0f; }

    const int w = tid >> 6, lane = tid & 63, q = lane >> 4, l15 = lane & 15;
    const bool isim = (pid < 384);
    int obj, p, nvalid;
    const float* src;
    unsigned short* dst;
    if (isim) {
        obj = pid / 3; p = pid % 3;
        src = im + (size_t)obj * 36 * DIM;
        dst = imp + (size_t)obj * AIMG + (size_t)p * APAN;
        nvalid = 36;
    } else {
        const int k = pid - 384;
        obj = k >> 2; p = k & 3;
        src = s + (size_t)obj * 60 * DIM;
        dst = sp + (size_t)obj * BCAP + (size_t)p * APAN;
        nvalid = 60;
    }
    const int row = p * 16 + l15;
    const bool valid = (row < nvalid);

    float ss = 0.0f;
    #pragma unroll
    for (int i = 0; i < 4; ++i) {
        const int c = w * 4 + i;
        #pragma unroll
        for (int h = 0; h < 2; ++h) {
            float4 v0 = make_float4(0.f, 0.f, 0.f, 0.f), v1 = v0;
            if (valid) {
                const float* rp = src + (size_t)row * DIM + c * 64 + h * 32 + q * 8;
                v0 = *(const float4*)rp;
                v1 = *(const float4*)(rp + 4);
            }
            ss += v0.x * v0.x + v0.y * v0.y + v0.z * v0.z + v0.w * v0.w
                + v1.x * v1.x + v1.y * v1.y + v1.z * v1.z + v1.w * v1.w;
            uint4 o;
            o.x = pkbf2(v0.x, v0.y); o.y = pkbf2(v0.z, v0.w);
            o.z = pkbf2(v1.x, v1.y); o.w = pkbf2(v1.z, v1.w);
            *(uint4*)(dst + (size_t)c * 1024 + h * 512 + q * 128 + l15 * 8) = o;
        }
    }
    ss = xq_sum(ss);
    __shared__ float sh[4][16];
    if (lane < 16) sh[w][lane] = ss;
    __syncthreads();
    if (tid < 16) {
        const float t = sh[0][tid] + sh[1][tid] + sh[2][tid] + sh[3][tid];
        const int r = p * 16 + tid;
        if (r < nvalid) {
            const float inv = 1.0f / (sqrtf(t) + EPS_F);
            if (isim) inv_im[obj * 36 + r] = inv;
            else      inv_cap[obj * 60 + r] = inv;
        }
    }
}

// ------- norms (fallback path only) -------

__global__ void norms_kernel(const float* __restrict__ im, const float* __restrict__ s,
                             float* __restrict__ inv_im, float* __restrict__ inv_cap,
                             float* __restrict__ out) {
    if (blockIdx.x == 0 && threadIdx.x == 0) { out[0] = 0.0f; out[1] = 0.0f; }
    const int NIM = N_IMAGE * N_REG;
    const int NS  = N_IMAGE * MAX_WORD;
    int row  = blockIdx.x * 4 + (threadIdx.x >> 6);
    int lane = threadIdx.x & 63;
    if (row >= NIM + NS) return;
    const bool isim = (row < NIM);
    const float* base = isim ? (im + (size_t)row * DIM)
                             : (s  + (size_t)(row - NIM) * DIM);
    const float4* b4 = (const float4*)base;
    float acc = 0.0f;
    for (int k = lane; k < DIM / 4; k += 64) {
        float4 v = b4[k];
        acc += v.x * v.x + v.y * v.y + v.z * v.z + v.w * v.w;
    }
    for (int off = 32; off; off >>= 1) acc += __shfl_down(acc, off, 64);
    if (lane == 0) {
        float inv = 1.0f / (sqrtf(acc) + EPS_F);
        if (isim) inv_im[row] = inv;
        else      inv_cap[row - NIM] = inv;
    }
}

// ---------------- A-matrix build (from MFMA acc -> packed A + col maxes) ----------------

template <int CT>
__device__ __forceinline__ void build_apk(
    f32x4 (&acc)[3 * CT], const float* invImS, const float* invCapS,
    int m, int wv, int q, int l15,
    unsigned int (*apk)[(CT + 1) / 2], float* mxv, bool* vw) {

    constexpr int PK = (CT + 1) / 2;
    float icap2[CT];                     // 2 * invCap (folded into the exp fma)
    #pragma unroll
    for (int ct = 0; ct < CT; ++ct) {
        const int w = ct * 16 + l15;
        vw[ct]    = (w < m);
        icap2[ct] = (w < 60) ? 2.0f * invCapS[w] : 0.0f;
    }
    #pragma unroll
    for (int ct = 0; ct < CT; ++ct) mxv[ct] = -3e38f;

    #pragma unroll
    for (int j = 0; j < 12; ++j) {
        const int rt = j >> 2, p = j & 3;
        const int r  = rt * 16 + q * 4 + p;                  // < 48
        const bool rowok = (rt < 2) || (q == 0);             // r < 36
        const float iir = rowok ? invImS[wv * 36 + (r < 36 ? r : 0)] : 0.0f;
        float av[CT];
        #pragma unroll
        for (int ct = 0; ct < CT; ++ct) {
            const float Mv = acc[rt * CT + ct][p];
            mxv[ct] = fmaxf(mxv[ct], rowok ? Mv : -3e38f);
            // A = exp(-2(1 - Mv*iir*icap)) = exp(fma(Mv, 2*iir*icap, -2))
            const bool ok = rowok && vw[ct];
            av[ct] = ok ? __expf(fmaf(Mv, iir * icap2[ct], -2.0f)) : 0.0f;
        }
        #pragma unroll
        for (int pk = 0; pk < PK; ++pk)
            apk[j][pk] = pkbf2(av[2 * pk], (2 * pk + 1 < CT) ? av[2 * pk + 1] : 0.0f);
    }

    // row-compress 12 -> 9 (rows 32..35 live at (j=8+p, q=0) -> slot (j=8, group q))
    {
        const int baddr = l15 << 2;
        #pragma unroll
        for (int pk = 0; pk < PK; ++pk) {
            const int r0 = __builtin_amdgcn_ds_bpermute(baddr, (int)apk[8][pk]);
            const int r1 = __builtin_amdgcn_ds_bpermute(baddr, (int)apk[9][pk]);
            const int r2 = __builtin_amdgcn_ds_bpermute(baddr, (int)apk[10][pk]);
            const int r3 = __builtin_amdgcn_ds_bpermute(baddr, (int)apk[11][pk]);
            const int lo = (q & 1) ? r1 : r0;
            const int hi = (q & 1) ? r3 : r2;
            apk[8][pk] = (unsigned int)((q & 2) ? hi : lo);
        }
    }
}

// ---------------- IPOT iteration core ----------------

template <int CT>
__device__ __forceinline__ float ot_iterate(
    f32x2 (*af)[(CT + 1) / 2], const bool* vw, float mf, float inv_m) {

    constexpr int PK = (CT + 1) / 2;
    f32x2 t2[9][PK];
    f32x2 sig2[PK];
    #pragma unroll
    for (int pk = 0; pk < PK; ++pk) {
        const bool v0 = vw[2 * pk];
        const bool v1 = (2 * pk + 1 < CT) && vw[2 * pk + 1];
        sig2[pk].x = v0 ? inv_m : 0.0f;
        sig2[pk].y = v1 ? inv_m : 0.0f;
        #pragma unroll
        for (int j = 0; j < 9; ++j) {
            t2[j][pk].x = v0 ? mf : 0.0f;
            t2[j][pk].y = v1 ? mf : 0.0f;
        }
    }

    for (int it = 0; it < OT_ITERS; ++it) {
        f32x2 s2[PK], csum[PK];
        #pragma unroll
        for (int pk = 0; pk < PK; ++pk) {
            s2[pk]   = sig2[pk] * sig2[pk];
            csum[pk] = (f32x2){0.0f, 0.0f};
        }
        #pragma unroll
        for (int j = 0; j < 9; ++j) {
            f32x2 at[PK];
            #pragma unroll
            for (int pk = 0; pk < PK; ++pk)
                at[pk] = af[j][pk] * t2[j][pk];
            f32x2 u2 = at[0] * s2[0];
            #pragma unroll
            for (int pk = 1; pk < PK; ++pk) u2 += at[pk] * s2[pk];
            const float R  = bfly16_sum(u2.x + u2.y);
            const float dl = __builtin_amdgcn_rcpf(36.0f * R);
            f32x2 dl2; dl2.x = dl; dl2.y = dl;
            #pragma unroll
            for (int pk = 0; pk < PK; ++pk) {
                const f32x2 tn = at[pk] * (dl2 * sig2[pk]);
                t2[j][pk] = tn;
                csum[pk] += tn;
            }
        }
        #pragma unroll
        for (int pk = 0; pk < PK; ++pk) {
            const float cx = xq_sum(csum[pk].x);
            const float cy = xq_sum(csum[pk].y);
            const bool v0 = vw[2 * pk];
            const bool v1 = (2 * pk + 1 < CT) && vw[2 * pk + 1];
            sig2[pk].x = v0 ? __builtin_amdgcn_rcpf(mf * cx) : 0.0f;
            sig2[pk].y = v1 ? __builtin_amdgcn_rcpf(mf * cy) : 0.0f;
        }
    }

    // -sum C.T ; C = -0.5 ln(A), T = t*sig
    float pp = 0.0f;
    #pragma unroll
    for (int j = 0; j < 9; ++j) {
        #pragma unroll
        for (int pk = 0; pk < PK; ++pk) {
            const float cvx = -0.5f * __logf(fmaxf(af[j][pk].x, 1e-30f));
            pp = fmaf(cvx, t2[j][pk].x * sig2[pk].x, pp);
            if (2 * pk + 1 < CT) {
                const float cvy = -0.5f * __logf(fmaxf(af[j][pk].y, 1e-30f));
                pp = fmaf(cvy, t2[j][pk].y * sig2[pk].y, pp);
            }
        }
    }
    return bfly64_sum(pp);
}

// ---------------- MISA from mxv ----------------

template <int CT>
__device__ __forceinline__ void misa_write(
    const float* mxv, const bool* vw, float inv_m, int lane,
    float* __restrict__ S, int b, int cap) {
    float sp = 0.0f;
    #pragma unroll
    for (int ct = 0; ct < CT; ++ct) {
        float v = xq_max(mxv[ct]);
        sp += vw[ct] ? v : 0.0f;
    }
    sp = bfly64_sum(sp);                 // = 4 * sum_w colmax (q-replicated)
    if (lane == 0) S[(size_t)b * N_IMAGE + cap] = sp * inv_m * 0.25f;
}

// ---------------- GEMM core (LDS-free, double-buffered — best-measured R2/R4) ----

template <int CT>
__device__ __forceinline__ void gemm_core(
    const unsigned short* __restrict__ imp, const unsigned short* __restrict__ sp,
    int cap, int b0, int wv, int q, int l15, f32x4 (&acc)[3 * CT]) {

    const unsigned short* Ab = imp + (size_t)(b0 + wv) * AIMG + (q * 128 + l15 * 8);
    const unsigned short* Bb = sp  + (size_t)cap * BCAP        + (q * 128 + l15 * 8);

    #pragma unroll
    for (int t = 0; t < 3 * CT; ++t) acc[t] = (f32x4){0.f, 0.f, 0.f, 0.f};

    bf16x8 a0[3], bf0[CT], a1[3], bf1[CT];
    #pragma unroll
    for (int rt = 0; rt < 3; ++rt) a0[rt] = *(const bf16x8*)(Ab + rt * APAN);
    #pragma unroll
    for (int ct = 0; ct < CT; ++ct) bf0[ct] = *(const bf16x8*)(Bb + ct * APAN);

    #pragma unroll 1
    for (int c = 0; c < 16; ++c) {
        const unsigned short* Ac = Ab + c * 1024;
        const unsigned short* Bc = Bb + c * 1024;
        #pragma unroll
        for (int rt = 0; rt < 3; ++rt) a1[rt] = *(const bf16x8*)(Ac + rt * APAN + 512);
        #pragma unroll
        for (int ct = 0; ct < CT; ++ct) bf1[ct] = *(const bf16x8*)(Bc + ct * APAN + 512);
        #pragma unroll
        for (int rt = 0; rt < 3; ++rt)
            #pragma unroll
            for (int ct = 0; ct < CT; ++ct)
                acc[rt * CT + ct] = __builtin_amdgcn_mfma_f32_16x16x32_bf16(
                    a0[rt], bf0[ct], acc[rt * CT + ct], 0, 0, 0);
        const int cn = (c < 15) ? c + 1 : 15;
        const unsigned short* An = Ab + cn * 1024;
        const unsigned short* Bn = Bb + cn * 1024;
        #pragma unroll
        for (int rt = 0; rt < 3; ++rt) a0[rt] = *(const bf16x8*)(An + rt * APAN);
        #pragma unroll
        for (int ct = 0; ct < CT; ++ct) bf0[ct] = *(const bf16x8*)(Bn + ct * APAN);
        #pragma unroll
        for (int rt = 0; rt < 3; ++rt)
            #pragma unroll
            for (int ct = 0; ct < CT; ++ct)
                acc[rt * CT + ct] = __builtin_amdgcn_mfma_f32_16x16x32_bf16(
                    a1[rt], bf1[ct], acc[rt * CT + ct], 0, 0, 0);
    }
}

// ---------------- fused pair kernel (LPT-ordered 1D grid) ----------------

template <int CT>
__device__ __forceinline__ void pair_body_fast(
    const unsigned short* __restrict__ imp, const unsigned short* __restrict__ sp,
    const float* invImS, const float* invCapS,
    int cap, int b0, int m,
    float* __restrict__ S, float* __restrict__ SOT) {

    const int tid  = threadIdx.x;
    const int lane = tid & 63;
    const int wv   = tid >> 6;
    const int q    = lane >> 4;
    const int l15  = lane & 15;
    const float mf    = (float)m;
    const float inv_m = 1.0f / mf;
    constexpr int PK = (CT + 1) / 2;

    f32x4 acc[3 * CT];
    gemm_core<CT>(imp, sp, cap, b0, wv, q, l15, acc);

    __syncthreads();

    unsigned int apk[12][PK];
    float mxv[CT]; bool vw[CT];
    build_apk<CT>(acc, invImS, invCapS, m, wv, q, l15, apk, mxv, vw);

    f32x2 af[9][PK];
    #pragma unroll
    for (int j = 0; j < 9; ++j)
        #pragma unroll
        for (int pk = 0; pk < PK; ++pk) {
            af[j][pk].x = lo16(apk[j][pk]);
            af[j][pk].y = hi16(apk[j][pk]);
        }

    const int b = b0 + wv;
    misa_write<CT>(mxv, vw, inv_m, lane, S, b, cap);
    const float pp = ot_iterate<CT>(af, vw, mf, inv_m);
    if (lane == 0) SOT[(size_t)b * N_IMAGE + cap] = -pp;
}

__global__ __launch_bounds__(256, 4)
void pair_fast(const unsigned short* __restrict__ imp,
               const unsigned short* __restrict__ sp,
               const int* __restrict__ s_l,
               const int* __restrict__ perm,
               const float* __restrict__ inv_im, const float* __restrict__ inv_cap,
               float* __restrict__ S, float* __restrict__ SOT) {
    // LPT order: blocks for the heaviest captions (largest m) dispatch first;
    // the grid tail is the lightest captions -> short drain tail.
    const int bid = blockIdx.x;              // [0, 4096)
    const int cap = perm[bid >> 5];          // sorted-descending caption
    const int b0  = (bid & 31) * 4;          // image group
    const int tid = threadIdx.x;

    __shared__ float invImS[144];
    __shared__ float invCapS[60];
    if (tid < 144) invImS[tid] = inv_im[b0 * 36 + tid];
    else if (tid < 204) invCapS[tid - 144] = inv_cap[cap * 60 + (tid - 144)];

    const int m  = s_l[cap];
    const int CT = __builtin_amdgcn_readfirstlane((m + 15) >> 4);
    switch (CT) {
    case 1: pair_body_fast<1>(imp, sp, invImS, invCapS, cap, b0, m, S, SOT); break;
    case 2: pair_body_fast<2>(imp, sp, invImS, invCapS, cap, b0, m, S, SOT); break;
    case 3: pair_body_fast<3>(imp, sp, invImS, invCapS, cap, b0, m, S, SOT); break;
    default: pair_body_fast<4>(imp, sp, invImS, invCapS, cap, b0, m, S, SOT); break;
    }
}

// ---------------- slow fallback (f32 inputs, LDS staging) ----------------

template <int CT>
__device__ __forceinline__ void pair_body_slow(
    const float* __restrict__ im, const float* __restrict__ s,
    char* smem, const float* invImS, const float* invCapS,
    int cap, int b0, int m,
    float* __restrict__ S, float* __restrict__ SOT) {

    const int tid  = threadIdx.x;
    const int lane = tid & 63;
    const int wv   = tid >> 6;
    const int q    = lane >> 4;
    const int l15  = lane & 15;
    const int q4   = tid & 15;
    const int row0 = tid >> 4;
    const float mf    = (float)m;
    const float inv_m = 1.0f / mf;
    constexpr int PK = (CT + 1) / 2;

    const char* sA = smem;
    const char* sB = smem + 27648;

    f32x4 acc[3 * CT];
    #pragma unroll
    for (int t = 0; t < 3 * CT; ++t) acc[t] = (f32x4){0.f, 0.f, 0.f, 0.f};

    for (int c = 0; c < 16; ++c) {
        const int col = c * 64 + q4 * 4;
        #pragma unroll
        for (int img = 0; img < 4; ++img) {
            #pragma unroll
            for (int j = 0; j < 3; ++j) {
                const int r = row0 + 16 * j;
                if (j < 2 || row0 < 4) {
                    const size_t ro = (size_t)(b0 * 36 + img * 36 + r) * 1024 + col;
                    float4 v = *(const float4*)(im + ro);
                    uint2 w2; w2.x = pkbf2(v.x, v.y); w2.y = pkbf2(v.z, v.w);
                    *(uint2*)(smem + (img * 48 + r) * 144 + q4 * 8) = w2;
                }
            }
        }
        #pragma unroll
        for (int j = 0; j < CT; ++j) {
            const int r = row0 + 16 * j;
            if (CT < 4 || j < 3 || row0 < 12) {
                const size_t ro = (size_t)(cap * 60 + r) * 1024 + col;
                float4 v = *(const float4*)(s + ro);
                uint2 w2; w2.x = pkbf2(v.x, v.y); w2.y = pkbf2(v.z, v.w);
                *(uint2*)(smem + (192 + r) * 144 + q4 * 8) = w2;
            }
        }
        __syncthreads();
        #pragma unroll
        for (int h = 0; h < 2; ++h) {
            bf16x8 bfr[CT];
            #pragma unroll
            for (int ct = 0; ct < CT; ++ct)
                bfr[ct] = *(const bf16x8*)(sB + (ct * 16 + l15) * 144 + h * 64 + q * 16);
            #pragma unroll
            for (int rt = 0; rt < 3; ++rt) {
                bf16x8 afr = *(const bf16x8*)(sA + (wv * 48 + rt * 16 + l15) * 144 + h * 64 + q * 16);
                #pragma unroll
                for (int ct = 0; ct < CT; ++ct)
                    acc[rt * CT + ct] = __builtin_amdgcn_mfma_f32_16x16x32_bf16(
                        afr, bfr[ct], acc[rt * CT + ct], 0, 0, 0);
            }
        }
        __syncthreads();
    }

    unsigned int apk[12][PK];
    float mxv[CT]; bool vw[CT];
    build_apk<CT>(acc, invImS, invCapS, m, wv, q, l15, apk, mxv, vw);

    f32x2 af[9][PK];
    #pragma unroll
    for (int j = 0; j < 9; ++j)
        #pragma unroll
        for (int pk = 0; pk < PK; ++pk) {
            af[j][pk].x = lo16(apk[j][pk]);
            af[j][pk].y = hi16(apk[j][pk]);
        }

    const int b = b0 + wv;
    misa_write<CT>(mxv, vw, inv_m, lane, S, b, cap);
    const float pp = ot_iterate<CT>(af, vw, mf, inv_m);
    if (lane == 0) SOT[(size_t)b * N_IMAGE + cap] = -pp;
}

__global__ __launch_bounds__(256, 4)
void pair_slow(const float* __restrict__ im, const float* __restrict__ s,
               const int* __restrict__ s_l,
               const float* __restrict__ inv_im, const float* __restrict__ inv_cap,
               float* __restrict__ S, float* __restrict__ SOT) {
    const int cap = blockIdx.x;
    const int b0  = blockIdx.y * 4;
    const int tid = threadIdx.x;

    __shared__ __align__(16) char smem[36864];
    __shared__ float invImS[144];
    __shared__ float invCapS[60];

    if (tid < 144) invImS[tid] = inv_im[b0 * 36 + tid];
    else if (tid < 204) invCapS[tid - 144] = inv_cap[cap * 60 + (tid - 144)];

    const int m = s_l[cap];
    {
        float4 z = make_float4(0.f, 0.f, 0.f, 0.f);
        #pragma unroll
        for (int j = 0; j < 9; ++j)
            *(float4*)(smem + (tid + j * 256) * 16) = z;
    }
    __syncthreads();

    const int CT = __builtin_amdgcn_readfirstlane((m + 15) >> 4);
    switch (CT) {
    case 1: pair_body_slow<1>(im, s, smem, invImS, invCapS, cap, b0, m, S, SOT); break;
    case 2: pair_body_slow<2>(im, s, smem, invImS, invCapS, cap, b0, m, S, SOT); break;
    case 3: pair_body_slow<3>(im, s, smem, invImS, invCapS, cap, b0, m, S, SOT); break;
    default: pair_body_slow<4>(im, s, smem, invImS, invCapS, cap, b0, m, S, SOT); break;
    }
}

// ---------------- loss ----------------

__global__ void loss_kernel(const float* __restrict__ S, const float* __restrict__ SOT,
                            float* __restrict__ out) {
    const int j = blockIdx.x;
    const int t = threadIdx.x;           // 128 threads
    __shared__ float sh[4][2];
    const float db  = S[j * 129];        // diag
    const float dob = SOT[j * 129];
    float rv = 0.f, rov = 0.f, cv = 0.f, cov = 0.f;
    if (t != j) {
        float cs  = fmaxf(0.0f, MARGIN_F + S[j * 128 + t] - db);
        float cso = fmaxf(0.0f, MARGIN_F + SOT[j * 128 + t] - dob);
        rv = cs + ALPHA_F * cso;  rov = cso;
        float ci  = fmaxf(0.0f, MARGIN_F + S[t * 128 + j] - db);
        float cio = fmaxf(0.0f, MARGIN_F + SOT[t * 128 + j] - dob);
        cv = ci + ALPHA_F * cio;  cov = cio;
    }
    for (int off = 32; off; off >>= 1) {
        rv  = fmaxf(rv,  __shfl_down(rv,  off, 64));
        rov = fmaxf(rov, __shfl_down(rov, off, 64));
        cv  = fmaxf(cv,  __shfl_down(cv,  off, 64));
        cov = fmaxf(cov, __shfl_down(cov, off, 64));
    }
    if ((t & 63) == 0) {
        sh[0][t >> 6] = rv; sh[1][t >> 6] = rov;
        sh[2][t >> 6] = cv; sh[3][t >> 6] = cov;
    }
    __syncthreads();
    if (t == 0) {
        float a0 = fmaxf(sh[0][0], sh[0][1]) + fmaxf(sh[2][0], sh[2][1]);
        float a1 = fmaxf(sh[1][0], sh[1][1]) + fmaxf(sh[3][0], sh[3][1]);
        atomicAdd(&out[0], a0);
        atomicAdd(&out[1], a1);
    }
}

extern "C" void kernel_launch(void* const* d_in, const int* in_sizes, int n_in,
                              void* d_out, int out_size, void* d_ws, size_t ws_size,
                              hipStream_t stream) {
    const float* im  = (const float*)d_in[0];
    const float* s   = (const float*)d_in[1];
    const int*   s_l = (const int*)d_in[2];
    float* out = (float*)d_out;
    float* ws  = (float*)d_ws;

    float* inv_im  = ws;
    float* inv_cap = ws + 4608;
    float* S       = ws + 12288;
    float* SOT     = ws + 28672;
    int*   perm    = (int*)(ws + 45056);                     // 128 ints
    // bf16 panels after the float+perm region (512 B for perm)
    unsigned short* imp = (unsigned short*)((char*)d_ws + 180736);
    unsigned short* sp  = imp + (size_t)N_IMAGE * AIMG;
    const size_t need_fast = 180736 +
        ((size_t)N_IMAGE * AIMG + (size_t)N_IMAGE * BCAP) * 2;   // 29,540,864

    if (ws_size >= need_fast) {
        pack_kernel<<<dim3(897), dim3(256), 0, stream>>>(
            im, s, inv_im, inv_cap, out, imp, sp, s_l, perm);
        pair_fast<<<dim3(N_IMAGE * N_IMAGE / 4), dim3(256), 0, stream>>>(
            imp, sp, s_l, perm, inv_im, inv_cap, S, SOT);
    } else {
        norms_kernel<<<dim3((4608 + 7680) / 4), dim3(256), 0, stream>>>(
            im, s, inv_im, inv_cap, out);
        pair_slow<<<dim3(N_IMAGE, N_IMAGE / 4), dim3(256), 0, stream>>>(
            im, s, s_l, inv_im, inv_cap, S, SOT);
    }
    loss_kernel<<<dim3(N_IMAGE), dim3(128), 0, stream>>>(S, SOT, out);
}